// Round 8
// baseline (619.358 us; speedup 1.0000x reference)
//
#include <hip/hip_runtime.h>

// ---------------------------------------------------------------------------
// Waveletnet: Haar DWT U-Net.
// R8 = R7 + XCD-colocating swizzle in cgemm: 1D grid, lin -> (m,n,k) with
// (n,k) in the low digits, so the NBM blocks sharing a B-slice have equal
// lin%8 -> same XCD -> B-slice fetched from HBM once, then L2-served.
// (R7: fragment-ordered LDS = 0 bank conflicts; double-buffered 1-barrier
// pipeline; pre-swizzled weights; bias chaining; fused wt/iwt layout kernels.)
// ---------------------------------------------------------------------------

#define TPB 256

typedef _Float16 f16x8 __attribute__((ext_vector_type(8)));
typedef float f32x4 __attribute__((ext_vector_type(4)));

#define GLOAD_LDS16(g, l)                                                     \
    __builtin_amdgcn_global_load_lds(                                         \
        (const __attribute__((address_space(1))) void*)(g),                   \
        (__attribute__((address_space(3))) void*)(l), 16, 0, 0)

// ---- spatial wt (fp32 -> fp32) --------------------------------------------
__global__ __launch_bounds__(TPB) void wt_k(const float* __restrict__ src,
                                            float* __restrict__ dst,
                                            int C, int H2, int W2) {
    int n = C * H2 * W2;
    int idx = blockIdx.x * TPB + threadIdx.x;
    if (idx >= n) return;
    int b = blockIdx.z;
    int c = idx / (H2 * W2);
    int p = idx - c * (H2 * W2);
    int h = p / W2, w = p - h * W2;
    int W = 2 * W2;
    const float* r = src + (((size_t)b * C + c) * (2 * H2) + 2 * h) * W + 2 * w;
    float a = r[0], bb = r[1], cc = r[W], dd = r[W + 1];
    size_t st = (size_t)H2 * W2;
    float* o = dst + (((size_t)b * 4 * C + 4 * c) * st) + p;
    o[0]      = 0.25f * (a + bb + cc + dd);
    o[st]     = (0.5f * (a + bb - cc - dd) + 1.0f) * 0.5f;
    o[2 * st] = (0.5f * (a - bb + cc - dd) + 1.0f) * 0.5f;
    o[3 * st] = (0.5f * (a - bb - cc + dd) + 1.0f) * 0.5f;
}

// ---- wt for step 7: spatial fp32 out (skip) + channels-last fp16 out -------
__global__ __launch_bounds__(TPB) void wt_dual_k(const float* __restrict__ src,
                                                 float* __restrict__ dst,
                                                 _Float16* __restrict__ X) {
    int idx = blockIdx.x * TPB + threadIdx.x;
    int b = blockIdx.z;
    int c = idx >> 8;
    int p = idx & 255;
    int h = p >> 4, w = p & 15;
    const float* r = src + (((size_t)b * 256 + c) * 32 + 2 * h) * 32 + 2 * w;
    float a = r[0], bb = r[1], cc = r[32], dd = r[33];
    float v0 = 0.25f * (a + bb + cc + dd);
    float v1 = (0.5f * (a + bb - cc - dd) + 1.0f) * 0.5f;
    float v2 = (0.5f * (a - bb + cc - dd) + 1.0f) * 0.5f;
    float v3 = (0.5f * (a - bb - cc + dd) + 1.0f) * 0.5f;
    float* o = dst + (((size_t)b * 1024 + 4 * c) * 256) + p;
    o[0] = v0; o[256] = v1; o[512] = v2; o[768] = v3;
    _Float16* q = X + ((size_t)(b * 256 + p)) * 1024 + 4 * c;
    q[0] = (_Float16)v0; q[1] = (_Float16)v1;
    q[2] = (_Float16)v2; q[3] = (_Float16)v3;
}

// ---- wt: spatial fp32 in -> channels-last fp16 out -------------------------
template <int LC>
__global__ __launch_bounds__(TPB) void wt_cl_k(const float* __restrict__ src,
                                               _Float16* __restrict__ X,
                                               int H2, int W2) {
    const int C = 1 << LC;
    int idx = blockIdx.x * TPB + threadIdx.x;
    int b = blockIdx.z;
    int c = idx & (C - 1);
    int p = idx >> LC;
    if (p >= H2 * W2) return;
    int h = p / W2, w = p - h * W2;
    int W = 2 * W2;
    const float* r = src + (((size_t)b * C + c) * (2 * H2) + 2 * h) * W + 2 * w;
    float a = r[0], bb = r[1], cc = r[W], dd = r[W + 1];
    _Float16* o = X + ((size_t)(b * H2 * W2 + p)) * (4 * C) + 4 * c;
    o[0] = (_Float16)(0.25f * (a + bb + cc + dd));
    o[1] = (_Float16)((0.5f * (a + bb - cc - dd) + 1.0f) * 0.5f);
    o[2] = (_Float16)((0.5f * (a - bb + cc - dd) + 1.0f) * 0.5f);
    o[3] = (_Float16)((0.5f * (a - bb - cc + dd) + 1.0f) * 0.5f);
}

// ---- spatial iwt (fp32 -> fp32) -------------------------------------------
__global__ __launch_bounds__(TPB) void iwt_k(const float* __restrict__ src,
                                             float* __restrict__ dst,
                                             int C, int H, int W) {
    int n = C * H * W;
    int idx = blockIdx.x * TPB + threadIdx.x;
    if (idx >= n) return;
    int b = blockIdx.z;
    int c = idx / (H * W);
    int p = idx - c * (H * W);
    int h = p / W, w = p - h * W;
    size_t st = (size_t)H * W;
    const float* r = src + ((size_t)b * 4 * C + 4 * c) * st + p;
    float v0 = r[0];
    float v1 = 2.0f * r[st] - 1.0f;
    float v2 = 2.0f * r[2 * st] - 1.0f;
    float v3 = 2.0f * r[3 * st] - 1.0f;
    float* o = dst + (((size_t)b * C + c) * (2 * H) + 2 * h) * (2 * W) + 2 * w;
    o[0]         = v0 + 0.5f * ( v1 + v2 + v3);
    o[1]         = v0 + 0.5f * ( v1 - v2 - v3);
    o[2 * W]     = v0 + 0.5f * (-v1 + v2 - v3);
    o[2 * W + 1] = v0 + 0.5f * (-v1 - v2 + v3);
}

// ---- iwt: spatial fp32 in -> channels-last fp16 (into concat slice) --------
template <int LC>
__global__ __launch_bounds__(TPB) void iwt_cl_k(const float* __restrict__ src,
                                                _Float16* __restrict__ X,
                                                int H, int W, int Coff, int Ctot) {
    const int C = 1 << LC;
    int idx = blockIdx.x * TPB + threadIdx.x;
    int b = blockIdx.z;
    int c = idx & (C - 1);
    int p = idx >> LC;
    if (p >= H * W) return;
    int h = p / W, w = p - h * W;
    size_t st = (size_t)H * W;
    const float* r = src + ((size_t)b * 4 * C + 4 * c) * st + p;
    float v0 = r[0];
    float v1 = 2.0f * r[st] - 1.0f;
    float v2 = 2.0f * r[2 * st] - 1.0f;
    float v3 = 2.0f * r[3 * st] - 1.0f;
    size_t mb = (size_t)b * 4 * H * W + (size_t)(2 * h) * (2 * W) + 2 * w;
    _Float16* o = X + mb * Ctot + Coff + c;
    o[0]                          = (_Float16)(v0 + 0.5f * ( v1 + v2 + v3));
    o[(size_t)Ctot]               = (_Float16)(v0 + 0.5f * ( v1 - v2 - v3));
    o[(size_t)(2 * W) * Ctot]     = (_Float16)(v0 + 0.5f * (-v1 + v2 - v3));
    o[(size_t)(2 * W + 1) * Ctot] = (_Float16)(v0 + 0.5f * (-v1 - v2 + v3));
}

// ---- generic direct 3x3 conv (conv1, convd2, convd1) -----------------------
template <int CO, bool LRELU, bool HAS_SKIP>
__global__ __launch_bounds__(TPB) void conv3x3_k(
    const float* __restrict__ s0, int C0,
    const float* __restrict__ s1,
    const float* __restrict__ wgt, const float* __restrict__ bias,
    const float* __restrict__ skip,
    float* __restrict__ out,
    int Cin, int Cout, int H, int W) {
    const int hw = H * W;
    int p = blockIdx.x * TPB + threadIdx.x;
    if (p >= hw) return;
    const int b = blockIdx.z;
    const int cog = blockIdx.y * CO;
    const int h = p / W, w = p - (p / W) * W;
    const bool hm = h > 0, hp = h < H - 1, wm = w > 0, wpp = w < W - 1;

    float acc[CO];
#pragma unroll
    for (int i = 0; i < CO; i++) acc[i] = bias[cog + i];

    const int C1n = Cin - C0;
    for (int ci = 0; ci < Cin; ci++) {
        const float* sp = (ci < C0)
            ? s0 + ((size_t)b * C0 + ci) * hw
            : s1 + ((size_t)b * C1n + (ci - C0)) * hw;
        const float* r = sp + p;
        float x00 = (hm && wm)  ? r[-W - 1] : 0.0f;
        float x01 = hm          ? r[-W]     : 0.0f;
        float x02 = (hm && wpp) ? r[-W + 1] : 0.0f;
        float x10 = wm          ? r[-1]     : 0.0f;
        float x11 =               r[0];
        float x12 = wpp         ? r[1]      : 0.0f;
        float x20 = (hp && wm)  ? r[W - 1]  : 0.0f;
        float x21 = hp          ? r[W]      : 0.0f;
        float x22 = (hp && wpp) ? r[W + 1]  : 0.0f;
        const float* wk = wgt + ((size_t)cog * Cin + ci) * 9;
#pragma unroll
        for (int i = 0; i < CO; i++) {
            const float* wi = wk + (size_t)i * Cin * 9;
            acc[i] += x00 * wi[0] + x01 * wi[1] + x02 * wi[2]
                    + x10 * wi[3] + x11 * wi[4] + x12 * wi[5]
                    + x20 * wi[6] + x21 * wi[7] + x22 * wi[8];
        }
    }
#pragma unroll
    for (int i = 0; i < CO; i++) {
        float v = acc[i];
        if (HAS_SKIP) v += skip[((size_t)b * Cout + cog + i) * hw + p];
        if (LRELU) v = (v >= 0.0f) ? v : 0.2f * v;
        out[((size_t)b * Cout + cog + i) * hw + p] = v;
    }
}

// ---- MFMA GEMM path --------------------------------------------------------

// Swizzled weight transform. Bh layout: chunks of 4KB = (nb64, kb32):
//   chunk = nb*(Kd/32)+kb; inside: [sub 0..3][lane 0..63][8 halfs]
//   co = nb*64 + sub*16 + (lane&15), k = kb*32 + ((lane>>4)&3)*8 + e.
__global__ __launch_bounds__(TPB) void wtrans_sw_k(const float* __restrict__ w,
                                                   _Float16* __restrict__ Bh,
                                                   int Cin, int KB, int n) {
    int idx = blockIdx.x * TPB + threadIdx.x;
    if (idx >= n) return;
    int e = idx & 7;
    int lane = (idx >> 3) & 63;
    int sub = (idx >> 9) & 3;
    int chunk = idx >> 11;
    int kb = chunk % KB;
    int nb = chunk / KB;
    int co = nb * 64 + sub * 16 + (lane & 15);
    int k = kb * 32 + ((lane >> 4) & 3) * 8 + e;
    int tap = k / Cin;
    int ci = k - tap * Cin;
    Bh[idx] = (_Float16)w[((size_t)co * Cin + ci) * 9 + tap];
}

// C[m][c] = bias[c] (initial seed for first GEMM only)
__global__ __launch_bounds__(TPB) void bias_mc_k(float* __restrict__ C,
                                                 const float* __restrict__ bias,
                                                 int mask) {
    int idx = blockIdx.x * TPB + threadIdx.x;
    C[idx] = bias[idx & mask];
}

// Pipelined, conflict-free fused implicit-im2col GEMM with XCD swizzle.
// 1D grid of NBM*NBN*KS blocks; lin -> (nk fast, m slow) so same-B blocks
// (same n,k; all m) have equal lin%8 -> same XCD -> B L2-shared.
// LC = log2(CIN); NT in {2,4}: block n-tile = NT*32. kc = K/KS, mult of 32.
template <int LC, int NT>
__global__ __launch_bounds__(TPB) void cgemm_k(
    const _Float16* __restrict__ X,
    const _Float16* __restrict__ Bw,   // swizzled (wtrans_sw_k layout)
    float* __restrict__ Cout,
    int Wimg, int kc, int N) {
    constexpr int CIN = 1 << LC;
    constexpr int Kd = 9 << LC;
    constexpr int KB = Kd >> 5;
    const int HW = Wimg * Wimg;
    const int NBN = N / (NT * 32);
    const int KS = Kd / kc;
    const int lin = blockIdx.x;
    const int nks = NBN * KS;
    const int nk = lin % nks;
    const int m0 = (lin / nks) * 128;
    const int n0 = (nk % NBN) * (NT * 32);
    const int k0 = (nk / NBN) * kc;
    const int iters = kc >> 5;

    __shared__ _Float16 As[2][4096];
    __shared__ _Float16 Bs[2][NT * 1024];

    const int tid = threadIdx.x;
    const int wave = tid >> 6, lane = tid & 63;
    const int wm = (wave >> 1) * 64;
    const int wn = (wave & 1) * (NT * 16);

    // A staging slots: q=0 -> addr16=tid, q=1 -> addr16=tid+256.
    int rh[2], rw[2], rbase[2], cq[2];
#pragma unroll
    for (int q = 0; q < 2; q++) {
        int a16 = tid + q * 256;
        int t = a16 >> 6, l = a16 & 63;
        int row = t * 16 + (l & 15);
        cq[q] = ((l >> 4) & 3) * 8;
        int m = m0 + row;
        int b = m / HW;
        int p = m - b * HW;
        rh[q] = p / Wimg;
        rw[q] = p - rh[q] * Wimg;
        rbase[q] = b * HW;
    }

    const int nb0 = n0 >> 6;
    const int kb0 = k0 >> 5;

#define STAGE_B(it, dbuf)                                                       \
    {                                                                           \
        int kb = kb0 + (it);                                                    \
        const char* g0 = (const char*)Bw +                                      \
            ((size_t)(nb0 * KB + kb) * 2048 + (size_t)tid * 8) * 2;             \
        GLOAD_LDS16(g0, (char*)&Bs[dbuf][0] + tid * 16);                        \
        if (NT == 4) {                                                          \
            const char* g1 = (const char*)Bw +                                  \
                ((size_t)((nb0 + 1) * KB + kb) * 2048 + (size_t)tid * 8) * 2;   \
            GLOAD_LDS16(g1, (char*)&Bs[dbuf][2048] + tid * 16);                 \
        }                                                                       \
    }

#define LOAD_A(it, a0v, a1v)                                                    \
    {                                                                           \
        const int kk = k0 + ((it) << 5);                                        \
        const int tap = kk >> LC;                                               \
        const int ci0 = kk & (CIN - 1);                                         \
        const int t3 = tap / 3;                                                 \
        const int dh = t3 - 1, dwv = tap - t3 * 3 - 1;                          \
        int hh0 = rh[0] + dh, ww0 = rw[0] + dwv;                                \
        a0v = (f16x8){0, 0, 0, 0, 0, 0, 0, 0};                                  \
        if ((unsigned)hh0 < (unsigned)Wimg && (unsigned)ww0 < (unsigned)Wimg)   \
            a0v = *(const f16x8*)(X +                                           \
                (((size_t)(rbase[0] + hh0 * Wimg + ww0)) << LC) + ci0 + cq[0]); \
        int hh1 = rh[1] + dh, ww1 = rw[1] + dwv;                                \
        a1v = (f16x8){0, 0, 0, 0, 0, 0, 0, 0};                                  \
        if ((unsigned)hh1 < (unsigned)Wimg && (unsigned)ww1 < (unsigned)Wimg)   \
            a1v = *(const f16x8*)(X +                                           \
                (((size_t)(rbase[1] + hh1 * Wimg + ww1)) << LC) + ci0 + cq[1]); \
    }

    f32x4 acc[4][NT];
#pragma unroll
    for (int i = 0; i < 4; i++)
#pragma unroll
        for (int j = 0; j < NT; j++) acc[i][j] = {0.f, 0.f, 0.f, 0.f};

    f16x8 a0, a1;
    STAGE_B(0, 0);
    LOAD_A(0, a0, a1);
    *(f16x8*)&As[0][(size_t)tid * 8] = a0;
    *(f16x8*)&As[0][(size_t)(tid + 256) * 8] = a1;
    __syncthreads();

    int buf = 0;
    for (int it = 0; it < iters; ++it) {
        const bool more = (it + 1) < iters;
        if (more) {
            STAGE_B(it + 1, buf ^ 1);     // DMA in flight across compute
            LOAD_A(it + 1, a0, a1);       // global->VGPR in flight
        }
        f16x8 af[4], bf[NT];
#pragma unroll
        for (int mt = 0; mt < 4; mt++)
            af[mt] = *(const f16x8*)&As[buf][((wm >> 4) + mt) * 512 + lane * 8];
#pragma unroll
        for (int nt = 0; nt < NT; nt++)
            bf[nt] = *(const f16x8*)&Bs[buf][((wn >> 4) + nt) * 512 + lane * 8];
#pragma unroll
        for (int mt = 0; mt < 4; mt++)
#pragma unroll
            for (int nt = 0; nt < NT; nt++)
                acc[mt][nt] = __builtin_amdgcn_mfma_f32_16x16x32_f16(
                    af[mt], bf[nt], acc[mt][nt], 0, 0, 0);
        if (more) {
            *(f16x8*)&As[buf ^ 1][(size_t)tid * 8] = a0;
            *(f16x8*)&As[buf ^ 1][(size_t)(tid + 256) * 8] = a1;
        }
        __syncthreads();
        buf ^= 1;
    }
#undef STAGE_B
#undef LOAD_A

    // epilogue: C/D layout col = lane&15, row = (lane>>4)*4 + reg
    const int cm = m0 + wm + (lane >> 4) * 4;
    const int cn = n0 + wn + (lane & 15);
#pragma unroll
    for (int mt = 0; mt < 4; mt++)
#pragma unroll
        for (int nt = 0; nt < NT; nt++)
#pragma unroll
            for (int r = 0; r < 4; r++)
                unsafeAtomicAdd(&Cout[(size_t)(cm + mt * 16 + r) * N + cn + nt * 16],
                                acc[mt][nt][r]);
}

// lrelu finalize from Cm[m][N]; optional spatial fp32, channels-last fp16,
// and next-layer bias chain write (per-element RMW at the read position).
template <bool SPAT, bool CL, bool NB>
__global__ __launch_bounds__(TPB) void fin_cl_k(float* __restrict__ Cm,
                                                float* __restrict__ spat,
                                                _Float16* __restrict__ X,
                                                int LN, int LHW, int Coff, int Ctot,
                                                const float* __restrict__ nbias,
                                                int nmask) {
    int idx = blockIdx.x * TPB + threadIdx.x;
    int m = idx >> LN;
    int c = idx & ((1 << LN) - 1);
    float v = Cm[idx];
    v = (v >= 0.0f) ? v : 0.2f * v;
    if (SPAT) {
        int b = m >> LHW;
        int p = m & ((1 << LHW) - 1);
        spat[(((size_t)(b << LN) + c) << LHW) + p] = v;
    }
    if (CL) X[(size_t)m * Ctot + Coff + c] = (_Float16)v;
    if (NB) Cm[idx] = nbias[idx & nmask];
}

// conv4 step-10 finalize: spatial out = lrelu(Cm[m][1024] + W4), + bias chain
template <bool NB>
__global__ __launch_bounds__(TPB) void fin_sp_k(float* __restrict__ Cm,
                                                const float* __restrict__ W4,
                                                float* __restrict__ out,
                                                const float* __restrict__ nbias,
                                                int nmask) {
    int idx = blockIdx.x * TPB + threadIdx.x;   // over 1M, (b,c,p)
    int b = idx >> 18;
    int r = idx & 262143;
    int c = r >> 8, p = r & 255;
    int m = (b << 8) + p;
    size_t pos = (size_t)m * 1024 + c;
    float v = Cm[pos] + W4[idx];
    out[idx] = (v >= 0.0f) ? v : 0.2f * v;
    if (NB) Cm[pos] = nbias[((int)pos) & nmask];
}

// Fused final iwt (12ch -> 3ch, 128->256) + 1x1 conv (3->3, no bias).
__global__ __launch_bounds__(TPB) void final_k(const float* __restrict__ src,
                                               const float* __restrict__ cf,
                                               float* __restrict__ out) {
    int p = blockIdx.x * TPB + threadIdx.x;
    int b = blockIdx.z;
    int h = p >> 7, w = p & 127;
    const int st = 128 * 128;
    float y00[3], y01[3], y10[3], y11[3];
    const float* r = src + (size_t)b * 12 * st + p;
#pragma unroll
    for (int c = 0; c < 3; c++) {
        float v0 = r[(4 * c) * st];
        float v1 = 2.0f * r[(4 * c + 1) * st] - 1.0f;
        float v2 = 2.0f * r[(4 * c + 2) * st] - 1.0f;
        float v3 = 2.0f * r[(4 * c + 3) * st] - 1.0f;
        y00[c] = v0 + 0.5f * ( v1 + v2 + v3);
        y01[c] = v0 + 0.5f * ( v1 - v2 - v3);
        y10[c] = v0 + 0.5f * (-v1 + v2 - v3);
        y11[c] = v0 + 0.5f * (-v1 - v2 + v3);
    }
#pragma unroll
    for (int o = 0; o < 3; o++) {
        float k0 = cf[o * 3], k1 = cf[o * 3 + 1], k2 = cf[o * 3 + 2];
        float* q = out + (((size_t)b * 3 + o) * 256 + 2 * h) * 256 + 2 * w;
        q[0]   = k0 * y00[0] + k1 * y00[1] + k2 * y00[2];
        q[1]   = k0 * y01[0] + k1 * y01[1] + k2 * y01[2];
        q[256] = k0 * y10[0] + k1 * y10[1] + k2 * y10[2];
        q[257] = k0 * y11[0] + k1 * y11[1] + k2 * y11[2];
    }
}

static inline void conv_launch(const float* s0, int C0, const float* s1,
                               const float* wgt, const float* bias,
                               float* out, int Cin, int Cout, int H, int W,
                               int CO, hipStream_t st) {
    dim3 grid((H * W + TPB - 1) / TPB, Cout / CO, 4);
    if (CO == 8)
        conv3x3_k<8, true, false><<<grid, TPB, 0, st>>>(s0, C0, s1, wgt, bias, nullptr, out, Cin, Cout, H, W);
    else
        conv3x3_k<4, true, false><<<grid, TPB, 0, st>>>(s0, C0, s1, wgt, bias, nullptr, out, Cin, Cout, H, W);
}

extern "C" void kernel_launch(void* const* d_in, const int* in_sizes, int n_in,
                              void* d_out, int out_size, void* d_ws, size_t ws_size,
                              hipStream_t stream) {
    (void)in_sizes; (void)n_in; (void)out_size; (void)ws_size;
    const float* x      = (const float*)d_in[0];
    const float* c1w    = (const float*)d_in[1];
    const float* c1b    = (const float*)d_in[2];
    const float* c2w    = (const float*)d_in[3];
    const float* c2b    = (const float*)d_in[4];
    const float* c3w    = (const float*)d_in[5];
    const float* c3b    = (const float*)d_in[6];
    const float* c4w    = (const float*)d_in[7];
    const float* c4b    = (const float*)d_in[8];
    const float* d4w    = (const float*)d_in[9];
    const float* d4b    = (const float*)d_in[10];
    const float* d3w    = (const float*)d_in[11];
    const float* d3b    = (const float*)d_in[12];
    const float* d2w    = (const float*)d_in[13];
    const float* d2b    = (const float*)d_in[14];
    const float* d1w    = (const float*)d_in[15];
    const float* d1b    = (const float*)d_in[16];
    const float* cfin   = (const float*)d_in[17];
    float* out = (float*)d_out;

    char* base = (char*)d_ws;
    const size_t MB = 1 << 20;
    float*    C1   = (float*)(base + 0 * MB);     // (4,16,128,128)
    float*    C3   = (float*)(base + 4 * MB);     // (4,256,32,32)
    float*    W4   = (float*)(base + 8 * MB);     // (4,1024,16,16)
    float*    TA   = (float*)(base + 12 * MB);
    float*    TB   = (float*)(base + 16 * MB);
    float*    C2   = (float*)(base + 20 * MB);    // (4,64,64,64)
    float*    Cmc  = (float*)(base + 24 * MB);    // GEMM acc, 1M floats
    _Float16* X0   = (_Float16*)(base + 28 * MB); // [1024][1024]
    _Float16* X1   = (_Float16*)(base + 30 * MB);
    _Float16* Xa   = (_Float16*)(base + 32 * MB); // w2 [16384][64] / w3 [4096][256]
    _Float16* Xd3  = (_Float16*)(base + 34 * MB); // [16384][128] concat(c2,t3)
    _Float16* Xd4  = (_Float16*)(base + 38 * MB); // [4096][512]  concat(c3,t4)
    _Float16* Bh4  = (_Float16*)(base + 42 * MB); // [1024][9216] 18 MiB
    _Float16* Bh3  = (_Float16*)(base + 60 * MB); // [256][2304]
    _Float16* Bhd4 = (_Float16*)(base + 62 * MB); // [256][4608]
    _Float16* Bhd3 = (_Float16*)(base + 65 * MB); // [64][1152]
    _Float16* Bh2  = (_Float16*)(base + 66 * MB); // [64][576]

    // swizzled weight transforms. n = Cout*9*Cin, KB = 9*Cin/32, grid = n/256.
    wtrans_sw_k<<<36864, TPB, 0, stream>>>(c4w, Bh4, 1024, 288, 9437184);
    wtrans_sw_k<<<2304,  TPB, 0, stream>>>(c3w, Bh3, 256, 72, 589824);
    wtrans_sw_k<<<4608,  TPB, 0, stream>>>(d4w, Bhd4, 512, 144, 1179648);
    wtrans_sw_k<<<288,   TPB, 0, stream>>>(d3w, Bhd3, 128, 36, 73728);
    wtrans_sw_k<<<144,   TPB, 0, stream>>>(c2w, Bh2, 64, 18, 36864);

    // 1. w1 = wt(x): (4,3,256,256) -> (4,12,128,128) spatial, in TA
    wt_k<<<dim3(192, 1, 4), TPB, 0, stream>>>(x, TA, 3, 128, 128);
    // 2. c1 = lrelu(conv1(w1)): 12 -> 16 @128^2 (generic)
    conv_launch(TA, 12, nullptr, c1w, c1b, C1, 12, 16, 128, 128, 8, stream);
    // 3. w2 = wt(c1) -> channels-last Xa [16384][64]
    wt_cl_k<4><<<dim3(256, 1, 4), TPB, 0, stream>>>(C1, Xa, 64, 64);
    // 4. c2 = lrelu(conv2(w2)): GEMM M=16384 N=64 K=576 (KS=3), 384 blocks
    bias_mc_k<<<4096, TPB, 0, stream>>>(Cmc, c2b, 63);
    cgemm_k<6, 2><<<384, TPB, 0, stream>>>(Xa, Bh2, Cmc, 64, 192, 64);
    fin_cl_k<true, true, true><<<4096, TPB, 0, stream>>>(Cmc, C2, Xd3, 6, 12, 0, 128, c3b, 255);
    // 5. w3 = wt(c2) -> channels-last Xa [4096][256]
    wt_cl_k<6><<<dim3(256, 1, 4), TPB, 0, stream>>>(C2, Xa, 32, 32);
    // 6. c3 = lrelu(conv3(w3)): GEMM M=4096 N=256 K=2304 (KS=8), 512 blocks
    cgemm_k<8, 4><<<512, TPB, 0, stream>>>(Xa, Bh3, Cmc, 32, 288, 256);
    fin_cl_k<true, true, true><<<4096, TPB, 0, stream>>>(Cmc, C3, Xd4, 8, 10, 0, 512, c4b, 1023);
    // 7. w4 = wt(c3) -> W4 spatial (skip) + X0 channels-last
    wt_dual_k<<<dim3(256, 1, 4), TPB, 0, stream>>>(C3, W4, X0);
    // 8. c4 = lrelu(conv4(w4)) -> X1   (M=N=1024, K=9216, KS=8), 512 blocks
    cgemm_k<10, 4><<<512, TPB, 0, stream>>>(X0, Bh4, Cmc, 16, 1152, 1024);
    fin_cl_k<false, true, true><<<4096, TPB, 0, stream>>>(Cmc, nullptr, X1, 10, 8, 0, 1024, c4b, 1023);
    // 9. c5 = lrelu(conv4(c4)) -> X0
    cgemm_k<10, 4><<<512, TPB, 0, stream>>>(X1, Bh4, Cmc, 16, 1152, 1024);
    fin_cl_k<false, true, true><<<4096, TPB, 0, stream>>>(Cmc, nullptr, X0, 10, 8, 0, 1024, c4b, 1023);
    // 10. ic4 = lrelu(conv4(c5) + w4) -> TA spatial; chain d4b
    cgemm_k<10, 4><<<512, TPB, 0, stream>>>(X0, Bh4, Cmc, 16, 1152, 1024);
    fin_sp_k<true><<<4096, TPB, 0, stream>>>(Cmc, W4, TA, d4b, 255);
    // 11. t4 = iwt(ic4) -> Xd4[:,256:512]
    iwt_cl_k<8><<<dim3(256, 1, 4), TPB, 0, stream>>>(TA, Xd4, 16, 16, 256, 512);
    // 12. ic3 = lrelu(convd4(c3||t4)): GEMM M=4096 N=256 K=4608 (KS=8), 512 blocks
    cgemm_k<9, 4><<<512, TPB, 0, stream>>>(Xd4, Bhd4, Cmc, 32, 576, 256);
    fin_cl_k<true, false, true><<<4096, TPB, 0, stream>>>(Cmc, TA, nullptr, 8, 10, 0, 0, d3b, 63);
    // 13. t3 = iwt(ic3) -> Xd3[:,64:128]
    iwt_cl_k<6><<<dim3(256, 1, 4), TPB, 0, stream>>>(TA, Xd3, 32, 32, 64, 128);
    // 14. ic2 = lrelu(convd3(c2||t3)): GEMM M=16384 N=64 K=1152 (KS=4), 512 blocks
    cgemm_k<7, 2><<<512, TPB, 0, stream>>>(Xd3, Bhd3, Cmc, 64, 288, 64);
    fin_cl_k<true, false, false><<<4096, TPB, 0, stream>>>(Cmc, TA, nullptr, 6, 12, 0, 0, nullptr, 0);
    // 15. t2 = iwt(ic2) -> TB spatial (4,16,128,128)
    iwt_k<<<dim3(256, 1, 4), TPB, 0, stream>>>(TA, TB, 16, 64, 64);
    // 16. ic1 = lrelu(convd2(c1||t2)): 32 -> 16 @128^2 (generic) -> TA
    conv_launch(C1, 16, TB, d2w, d2b, TA, 32, 16, 128, 128, 8, stream);
    // 17. iw1 = lrelu(convd1(ic1)): 16 -> 12 @128^2 (generic) -> TB
    conv_launch(TA, 16, TA, d1w, d1b, TB, 16, 12, 128, 128, 4, stream);
    // 18. out = 1x1(iwt(iw1)) fused
    final_k<<<dim3(64, 1, 4), TPB, 0, stream>>>(TB, cfin, out);
}